// Round 8
// baseline (185.226 us; speedup 1.0000x reference)
//
#include <hip/hip_runtime.h>
#include <hip/hip_bf16.h>

#define HH 1024
#define LL 512
#define NT 16              // 512/32 row-tiles
#define NTRI 136           // NT*(NT+1)/2 triangular tiles

typedef __attribute__((ext_vector_type(8))) short bf16x8;
typedef __attribute__((ext_vector_type(4))) float f32x4;

static constexpr float C_EXP = 2.8853900817779268f; // 2*log2(e)

// pack 8 fp32 -> 8 bf16 (RNE) as uint4
static __device__ __forceinline__ uint4 pack8(float4 a, float4 b) {
    union { uint4 u; __hip_bfloat162 h[4]; } r;
    r.h[0] = __float22bfloat162_rn(make_float2(a.x, a.y));
    r.h[1] = __float22bfloat162_rn(make_float2(a.z, a.w));
    r.h[2] = __float22bfloat162_rn(make_float2(b.x, b.y));
    r.h[3] = __float22bfloat162_rn(make_float2(b.z, b.w));
    return r.u;
}

// ---------------------------------------------------------------------------
// Kernel 0: fp32->bf16 convert (lm 1MB, W1 4MB) + wsum[c] = sum_h W2[c,h].
//   B16[n][k] = bf16(W1[(n&1023)*2048 + (n>>10)*1024 + k])   n<1024: Wa, else Wb
// ---------------------------------------------------------------------------
__global__ __launch_bounds__(256) void convert_kernel(
    const float* __restrict__ lm, const float* __restrict__ W1,
    const float* __restrict__ W2,
    ushort* __restrict__ lm16, ushort* __restrict__ B16, float* __restrict__ wsum)
{
    const int b = blockIdx.x;
    if (b == 1280) {
        const int tid = threadIdx.x;
        if (tid < 128) {
            const int c = tid >> 6, l = tid & 63;
            float s = 0.f;
            for (int q = l; q < 256; q += 64) {
                const float4 v = *(const float4*)&W2[c * HH + q * 4];
                s += v.x + v.y + v.z + v.w;
            }
#pragma unroll
            for (int off = 32; off; off >>= 1) s += __shfl_down(s, off, 64);
            if (l == 0) wsum[c] = s;
        }
        return;
    }
    const int q = b * 256 + threadIdx.x;            // 8-elem group
    if (q < 65536) {                                // lm: 512*1024/8
        const float4 a = *(const float4*)&lm[q * 8];
        const float4 c = *(const float4*)&lm[q * 8 + 4];
        ((uint4*)lm16)[q] = pack8(a, c);
    } else {
        const int p = q - 65536;                    // 0..262143
        const int n = p >> 7, k8 = (p & 127) * 8;
        const float* src = &W1[(n & 1023) * 2048 + (n >> 10) * 1024 + k8];
        ((uint4*)B16)[p] = pack8(*(const float4*)src, *(const float4*)(src + 4));
    }
}

// ---------------------------------------------------------------------------
// Kernel 1: big-tile bf16 MFMA projection (m97-style compute density).
// Tile 64m x 128n, BK=64. Each of 4 waves owns a 16m strip x all 128n
// (8 MFMA tiles, 32 acc VGPRs). Grid (16,8) = 128 blocks.
// Traffic: A 16MB + B 32MB (vs 160MB for the 16x64 tiling); 16 barriered
// iters with 16 MFMA/wave each (vs 4) -- latency per MFMA cut ~8x.
//   n < 1024:  Ea[m][n] = exp2(C*(acc+b1[n]));  else Eb[m][n-1024] = exp2(C*acc)
// ---------------------------------------------------------------------------
__global__ __launch_bounds__(256) void proj_mfma_kernel(
    const ushort* __restrict__ lm16, const ushort* __restrict__ B16,
    const float* __restrict__ b1, float* __restrict__ Ea, float* __restrict__ Eb)
{
    __shared__ ushort As[64][72];   // 72 us = 36 dw = 4 mod 32 banks: <=2-way, free
    __shared__ ushort Bs[128][72];

    const int tid  = threadIdx.x;
    const int lane = tid & 63;
    const int w    = tid >> 6;
    const int nbase = blockIdx.x * 128;   // 0..1920
    const int mbase = blockIdx.y * 64;    // 0..448
    const int wm   = w * 16;

    const int frow = lane & 15;
    const int q8   = (lane >> 4) * 8;

    f32x4 acc[8] = {};

    for (int kb = 0; kb < HH; kb += 64) {
        __syncthreads();
        {   // As: 64 rows x 64 bf16 = 512 uint4 slots, 2/thread
            int p = tid;
#pragma unroll
            for (int it = 0; it < 2; ++it, p += 256) {
                const int row = p >> 3, c8 = (p & 7) * 8;
                *(uint4*)&As[row][c8] = *(const uint4*)&lm16[(mbase + row) * HH + kb + c8];
            }
            // Bs: 128 rows = 1024 slots, 4/thread
            p = tid;
#pragma unroll
            for (int it = 0; it < 4; ++it, p += 256) {
                const int row = p >> 3, c8 = (p & 7) * 8;
                *(uint4*)&Bs[row][c8] = *(const uint4*)&B16[(nbase + row) * HH + kb + c8];
            }
        }
        __syncthreads();

#pragma unroll
        for (int s = 0; s < 2; ++s) {
            const bf16x8 a = *(const bf16x8*)&As[wm + frow][s * 32 + q8];
#pragma unroll
            for (int nf = 0; nf < 8; ++nf) {
                const bf16x8 bb = *(const bf16x8*)&Bs[nf * 16 + frow][s * 32 + q8];
                acc[nf] = __builtin_amdgcn_mfma_f32_16x16x32_bf16(a, bb, acc[nf], 0, 0, 0);
            }
        }
    }

    // D mapping: col=lane&15 (n), row=(lane>>4)*4+reg (m)
    const int col = lane & 15;
    const int rq  = (lane >> 4) * 4;
    const int m0  = mbase + wm + rq;
    const bool isA = nbase < HH;          // block-uniform
#pragma unroll
    for (int nf = 0; nf < 8; ++nf) {
        const int nn = (nbase + nf * 16 + col) & 1023;
        if (isA) {
            const float bb = b1[nn];
#pragma unroll
            for (int r = 0; r < 4; ++r)
                Ea[(m0 + r) * HH + nn] = __builtin_amdgcn_exp2f(C_EXP * (acc[nf][r] + bb));
        } else {
#pragma unroll
            for (int r = 0; r < 4; ++r)
                Eb[(m0 + r) * HH + nn] = __builtin_amdgcn_exp2f(C_EXP * acc[nf][r]);
        }
    }
}

// ---------------------------------------------------------------------------
// Kernel 2: triangular pairwise contraction (round-6 config, best measured).
//   u = 1/(Ea[j,h]*Eb[i,h]+1) + 1/(Ea[i,h]*Eb[j,h]+1)
//   pbuf = sum_slice u * W2[c,h]     (out = wsum + b2 - sum_z pbuf in combine)
// Block = (bi<=bj) 32x32 tile pair x one 64-h slice (nz=16: single K-iter).
// Thread owns 2i x 2j; batched rcp (1 per 4 denominators). Plain stores.
// ---------------------------------------------------------------------------
__global__ __launch_bounds__(256, 4) void pair_kernel(
    const float* __restrict__ Ea, const float* __restrict__ Eb,
    const float* __restrict__ W2, float* __restrict__ pbuf, int nz)
{
    __shared__ float eaj[32][68];   // stride 68 = 4 mod 32 banks: <=2-way, free
    __shared__ float eai[32][68];
    __shared__ float ebi[32][68];
    __shared__ float ebj[32][68];
    __shared__ float w0_s[256], w1_s[256];

    const int tid = threadIdx.x;
    const int tx  = tid & 15;
    const int ty  = tid >> 4;

    int tt = blockIdx.x, bi = 0, rem = NT;          // triangular decode
    while (tt >= rem) { tt -= rem; --rem; ++bi; }
    const int bj    = bi + tt;
    const int ibase = bi * 32;
    const int jbase = bj * 32;
    const int slice = HH / nz;
    const int k0    = blockIdx.y * slice;

    {   // stage W2 slice
        const int nf4 = slice >> 2;
        if (tid < 2 * nf4) {
            const int c = tid >= nf4, q = tid - c * nf4;
            ((float4*)(c ? w1_s : w0_s))[q] = *(const float4*)&W2[c * HH + k0 + q * 4];
        }
    }

    float acc[2][2][2] = {};  // [ii][jj][c]

    for (int kb = 0; kb < slice; kb += 64) {
        __syncthreads();
        {   // stage 4 tiles x 32 rows x 64 floats = 2048 float4, 8/thread
            int p = tid;
#pragma unroll
            for (int it = 0; it < 8; ++it, p += 256) {
                const int tile = p >> 9;
                const int row  = (p >> 4) & 31;
                const int c4   = p & 15;
                float4 v;
                if      (tile == 0) v = *(const float4*)&Ea[(jbase + row) * HH + k0 + kb + c4 * 4];
                else if (tile == 1) v = *(const float4*)&Ea[(ibase + row) * HH + k0 + kb + c4 * 4];
                else if (tile == 2) v = *(const float4*)&Eb[(ibase + row) * HH + k0 + kb + c4 * 4];
                else                v = *(const float4*)&Eb[(jbase + row) * HH + k0 + kb + c4 * 4];
                if      (tile == 0) *(float4*)&eaj[row][c4 * 4] = v;
                else if (tile == 1) *(float4*)&eai[row][c4 * 4] = v;
                else if (tile == 2) *(float4*)&ebi[row][c4 * 4] = v;
                else                *(float4*)&ebj[row][c4 * 4] = v;
            }
        }
        __syncthreads();

#pragma unroll 4
        for (int h4 = 0; h4 < 16; ++h4) {
            const float4 Aj0 = *(const float4*)&eaj[tx][h4 * 4];
            const float4 Aj1 = *(const float4*)&eaj[tx + 16][h4 * 4];
            const float4 Bi0 = *(const float4*)&ebi[ty][h4 * 4];
            const float4 Bi1 = *(const float4*)&ebi[ty + 16][h4 * 4];
            const float4 Ai0 = *(const float4*)&eai[ty][h4 * 4];
            const float4 Ai1 = *(const float4*)&eai[ty + 16][h4 * 4];
            const float4 Bj0 = *(const float4*)&ebj[tx][h4 * 4];
            const float4 Bj1 = *(const float4*)&ebj[tx + 16][h4 * 4];
            const float4 w0  = *(const float4*)&w0_s[kb + h4 * 4];  // broadcast
            const float4 w1  = *(const float4*)&w1_s[kb + h4 * 4];

#define DO_H(AJ0, AJ1, BI0, BI1, AI0, AI1, BJ0, BJ1, W0V, W1V)        \
            {                                                          \
                const float d00 = __builtin_fmaf((BI0), (AJ0), 1.f);   \
                const float d01 = __builtin_fmaf((BI0), (AJ1), 1.f);   \
                const float d10 = __builtin_fmaf((BI1), (AJ0), 1.f);   \
                const float d11 = __builtin_fmaf((BI1), (AJ1), 1.f);   \
                const float e00 = __builtin_fmaf((AI0), (BJ0), 1.f);   \
                const float e01 = __builtin_fmaf((AI0), (BJ1), 1.f);   \
                const float e10 = __builtin_fmaf((AI1), (BJ0), 1.f);   \
                const float e11 = __builtin_fmaf((AI1), (BJ1), 1.f);   \
                const float dp0 = d00 * d01, dp1 = d10 * d11;          \
                const float DR  = __builtin_amdgcn_rcpf(dp0 * dp1);    \
                const float dq0 = DR * dp1, dq1 = DR * dp0;            \
                const float rd00 = dq0 * d01, rd01 = dq0 * d00;        \
                const float rd10 = dq1 * d11, rd11 = dq1 * d10;        \
                const float ep0 = e00 * e01, ep1 = e10 * e11;          \
                const float ER  = __builtin_amdgcn_rcpf(ep0 * ep1);    \
                const float eq0 = ER * ep1, eq1 = ER * ep0;            \
                const float re00 = eq0 * e01, re01 = eq0 * e00;        \
                const float re10 = eq1 * e11, re11 = eq1 * e10;        \
                const float u00 = rd00 + re00, u01 = rd01 + re01;      \
                const float u10 = rd10 + re10, u11 = rd11 + re11;      \
                acc[0][0][0] = __builtin_fmaf(u00, (W0V), acc[0][0][0]); \
                acc[0][0][1] = __builtin_fmaf(u00, (W1V), acc[0][0][1]); \
                acc[0][1][0] = __builtin_fmaf(u01, (W0V), acc[0][1][0]); \
                acc[0][1][1] = __builtin_fmaf(u01, (W1V), acc[0][1][1]); \
                acc[1][0][0] = __builtin_fmaf(u10, (W0V), acc[1][0][0]); \
                acc[1][0][1] = __builtin_fmaf(u10, (W1V), acc[1][0][1]); \
                acc[1][1][0] = __builtin_fmaf(u11, (W0V), acc[1][1][0]); \
                acc[1][1][1] = __builtin_fmaf(u11, (W1V), acc[1][1][1]); \
            }
            DO_H(Aj0.x, Aj1.x, Bi0.x, Bi1.x, Ai0.x, Ai1.x, Bj0.x, Bj1.x, w0.x, w1.x)
            DO_H(Aj0.y, Aj1.y, Bi0.y, Bi1.y, Ai0.y, Ai1.y, Bj0.y, Bj1.y, w0.y, w1.y)
            DO_H(Aj0.z, Aj1.z, Bi0.z, Bi1.z, Ai0.z, Ai1.z, Bj0.z, Bj1.z, w0.z, w1.z)
            DO_H(Aj0.w, Aj1.w, Bi0.w, Bi1.w, Ai0.w, Ai1.w, Bj0.w, Bj1.w, w0.w, w1.w)
#undef DO_H
        }
    }

    float* pb = pbuf + ((size_t)blockIdx.y * NTRI + blockIdx.x) * 2048;
#pragma unroll
    for (int ii = 0; ii < 2; ++ii)
#pragma unroll
        for (int jj = 0; jj < 2; ++jj) {
            const int li = ty + ii * 16, lj = tx + jj * 16;
            *(float2*)&pb[(li * 32 + lj) * 2] =
                make_float2(acc[ii][jj][0], acc[ii][jj][1]);
        }
}

// ---------------------------------------------------------------------------
// Kernel 3: combine: out = wsum[c]+b2[c] - sum_z pbuf; both (i,j) and (j,i)
// stores made coalesced via an LDS transpose. One block per tri-tile (136).
// ---------------------------------------------------------------------------
__global__ __launch_bounds__(256) void combine_kernel(
    const float* __restrict__ pbuf, const float* __restrict__ b2,
    const float* __restrict__ wsum, float* __restrict__ out, int nz)
{
    __shared__ float ts[2][32][33];

    const int tid = threadIdx.x;
    const int t   = blockIdx.x;
    int tt = t, bi = 0, rem = NT;
    while (tt >= rem) { tt -= rem; --rem; ++bi; }
    const int bj = bi + tt;

    const float base0 = wsum[0] + b2[0];
    const float base1 = wsum[1] + b2[1];

#pragma unroll
    for (int k = 0; k < 8; ++k) {
        const int local = k * 256 + tid;          // li*64 + lj*2 + c
        float s = 0.f;
        for (int z = 0; z < nz; ++z)
            s += pbuf[((size_t)z * NTRI + t) * 2048 + local];
        const int li = local >> 6;
        const int lj = (local >> 1) & 31;
        const int c  = local & 1;
        const float v = (c ? base1 : base0) - s;
        ts[c][li][lj] = v;
        // direct (i,j) store: consecutive threads -> consecutive addresses
        out[((bi * 32 + li) * LL + bj * 32 + lj) * 2 + c] = v;
    }
    __syncthreads();
#pragma unroll
    for (int k = 0; k < 8; ++k) {
        const int local = k * 256 + tid;          // lj*64 + li*2 + c
        const int lj = local >> 6;
        const int li = (local >> 1) & 31;
        const int c  = local & 1;
        // transposed (j,i) store: also coalesced (diag tiles: benign rewrite)
        out[((bj * 32 + lj) * LL + bi * 32 + li) * 2 + c] = ts[c][li][lj];
    }
}

extern "C" void kernel_launch(void* const* d_in, const int* in_sizes, int n_in,
                              void* d_out, int out_size, void* d_ws, size_t ws_size,
                              hipStream_t stream)
{
    const float* lm = (const float*)d_in[0];
    const float* W1 = (const float*)d_in[1];
    const float* b1 = (const float*)d_in[2];
    const float* W2 = (const float*)d_in[3];
    const float* b2 = (const float*)d_in[4];
    float* out = (float*)d_out;

    char* ws = (char*)d_ws;
    float*  Ea   = (float*)ws;                           // 2 MB
    float*  Eb   = (float*)(ws + (2u << 20));            // 2 MB
    ushort* lm16 = (ushort*)(ws + (4u << 20));           // 1 MB
    ushort* B16  = (ushort*)(ws + (5u << 20));           // 4 MB
    float*  wsum = (float*)(ws + (9u << 20));            // 256 B
    float*  pbuf = (float*)(ws + (9u << 20) + 256);      // nz * 1.11 MB

    const size_t base = (9u << 20) + 256;
    int nz = 16;
    while (nz > 4 && base + (size_t)nz * NTRI * 2048 * 4 > ws_size) nz >>= 1;

    convert_kernel<<<1281, 256, 0, stream>>>(lm, W1, W2, lm16, B16, wsum);
    proj_mfma_kernel<<<dim3(16, 8), 256, 0, stream>>>(lm16, B16, b1, Ea, Eb);
    pair_kernel<<<dim3(NTRI, nz), 256, 0, stream>>>(Ea, Eb, W2, pbuf, nz);
    combine_kernel<<<NTRI, 256, 0, stream>>>(pbuf, b2, wsum, out, nz);
}

// Round 9
// 135.617 us; speedup vs baseline: 1.3658x; 1.3658x over previous
//
#include <hip/hip_runtime.h>
#include <hip/hip_bf16.h>

#define HH 1024
#define LL 512
#define NT 16              // 512/32 row-tiles
#define NTRI 136           // NT*(NT+1)/2 triangular tiles
#define NZ 8               // h-slices in pair kernel (slice = 128)

typedef __attribute__((ext_vector_type(8))) short bf16x8;
typedef __attribute__((ext_vector_type(4))) float f32x4;

static constexpr float C_EXP = 2.8853900817779268f; // 2*log2(e)

// pack 8 fp32 -> 8 bf16 (RNE) as uint4
static __device__ __forceinline__ uint4 pack8(float4 a, float4 b) {
    union { uint4 u; __hip_bfloat162 h[4]; } r;
    r.h[0] = __float22bfloat162_rn(make_float2(a.x, a.y));
    r.h[1] = __float22bfloat162_rn(make_float2(a.z, a.w));
    r.h[2] = __float22bfloat162_rn(make_float2(b.x, b.y));
    r.h[3] = __float22bfloat162_rn(make_float2(b.z, b.w));
    return r.u;
}

// ---------------------------------------------------------------------------
// Kernel 0: fp32->bf16 convert (lm 1MB, W1 4MB) + wsum[c] = sum_h W2[c,h].
//   B16[n][k] = bf16(W1[(n&1023)*2048 + (n>>10)*1024 + k])   n<1024: Wa, else Wb
// ---------------------------------------------------------------------------
__global__ __launch_bounds__(256) void convert_kernel(
    const float* __restrict__ lm, const float* __restrict__ W1,
    const float* __restrict__ W2,
    ushort* __restrict__ lm16, ushort* __restrict__ B16, float* __restrict__ wsum)
{
    const int b = blockIdx.x;
    if (b == 1280) {
        const int tid = threadIdx.x;
        if (tid < 128) {
            const int c = tid >> 6, l = tid & 63;
            float s = 0.f;
            for (int q = l; q < 256; q += 64) {
                const float4 v = *(const float4*)&W2[c * HH + q * 4];
                s += v.x + v.y + v.z + v.w;
            }
#pragma unroll
            for (int off = 32; off; off >>= 1) s += __shfl_down(s, off, 64);
            if (l == 0) wsum[c] = s;
        }
        return;
    }
    const int q = b * 256 + threadIdx.x;            // 8-elem group
    if (q < 65536) {                                // lm: 512*1024/8
        const float4 a = *(const float4*)&lm[q * 8];
        const float4 c = *(const float4*)&lm[q * 8 + 4];
        ((uint4*)lm16)[q] = pack8(a, c);
    } else {
        const int p = q - 65536;                    // 0..262143
        const int n = p >> 7, k8 = (p & 127) * 8;
        const float* src = &W1[(n & 1023) * 2048 + (n >> 10) * 1024 + k8];
        ((uint4*)B16)[p] = pack8(*(const float4*)src, *(const float4*)(src + 4));
    }
}

// ---------------------------------------------------------------------------
// Kernel 1: bf16 MFMA projection. Tile 64m x 64n, BK=64, grid 256 = 1/CU
// (every CU active). Each of 4 waves owns a 16m strip x 64n (4 frags).
// XCD swizzle: xcd=b&7 owns 4 nbase values (512KB B16 slice, L2-resident) x
// all 8 mbase. Re-read traffic worst-case 64MB (L3), best-case L2-served.
//   n < 1024:  Ea[m][n] = exp2(C*(acc+b1[n]));  else Eb[m][n-1024] = exp2(C*acc)
// ---------------------------------------------------------------------------
__global__ __launch_bounds__(256, 4) void proj_mfma_kernel(
    const ushort* __restrict__ lm16, const ushort* __restrict__ B16,
    const float* __restrict__ b1, float* __restrict__ Ea, float* __restrict__ Eb)
{
    __shared__ ushort As[64][72];   // 72 us = 36 dw = 4 mod 32 banks: <=2-way, free
    __shared__ ushort Bs[64][72];

    const int tid  = threadIdx.x;
    const int lane = tid & 63;
    const int w    = tid >> 6;
    const int b    = blockIdx.x;          // 0..255
    const int xcd  = b & 7;
    const int idx  = b >> 3;              // 0..31
    const int nbase = (xcd * 4 + (idx & 3)) * 64;   // 0..2047
    const int mbase = (idx >> 2) * 64;              // 0..448
    const int wm   = w * 16;

    const int frow = lane & 15;
    const int q8   = (lane >> 4) * 8;

    f32x4 acc[4] = {};

    for (int kb = 0; kb < HH; kb += 64) {
        __syncthreads();
        {   // As/Bs: 64 rows x 64 bf16 = 512 uint4 slots each, 2/thread each
            int p = tid;
#pragma unroll
            for (int it = 0; it < 2; ++it, p += 256) {
                const int row = p >> 3, c8 = (p & 7) * 8;
                *(uint4*)&As[row][c8] = *(const uint4*)&lm16[(mbase + row) * HH + kb + c8];
                *(uint4*)&Bs[row][c8] = *(const uint4*)&B16[(nbase + row) * HH + kb + c8];
            }
        }
        __syncthreads();

#pragma unroll
        for (int s = 0; s < 2; ++s) {
            const bf16x8 a = *(const bf16x8*)&As[wm + frow][s * 32 + q8];
#pragma unroll
            for (int nf = 0; nf < 4; ++nf) {
                const bf16x8 bb = *(const bf16x8*)&Bs[nf * 16 + frow][s * 32 + q8];
                acc[nf] = __builtin_amdgcn_mfma_f32_16x16x32_bf16(a, bb, acc[nf], 0, 0, 0);
            }
        }
    }

    // D mapping: col=lane&15 (n), row=(lane>>4)*4+reg (m)
    const int col = lane & 15;
    const int rq  = (lane >> 4) * 4;
    const int m0  = mbase + wm + rq;
    const bool isA = nbase < HH;          // block-uniform
#pragma unroll
    for (int nf = 0; nf < 4; ++nf) {
        const int nn = (nbase + nf * 16 + col) & 1023;
        if (isA) {
            const float bb = b1[nn];
#pragma unroll
            for (int r = 0; r < 4; ++r)
                Ea[(m0 + r) * HH + nn] = __builtin_amdgcn_exp2f(C_EXP * (acc[nf][r] + bb));
        } else {
#pragma unroll
            for (int r = 0; r < 4; ++r)
                Eb[(m0 + r) * HH + nn] = __builtin_amdgcn_exp2f(C_EXP * acc[nf][r]);
        }
    }
}

// ---------------------------------------------------------------------------
// Kernel 2: triangular pairwise contraction (R6 config — best measured 49us).
//   u = 1/(Ea[j,h]*Eb[i,h]+1) + 1/(Ea[i,h]*Eb[j,h]+1)
//   pbuf = sum_slice u * W2[c,h]     (out = wsum + b2 - sum_z pbuf in combine)
// Block = (bi<=bj) 32x32 tile pair x one 128-h slice. Thread owns 2i x 2j.
// Batched rcp (1 per 4 denominators). Plain stores, no atomics.
// ---------------------------------------------------------------------------
__global__ __launch_bounds__(256, 4) void pair_kernel(
    const float* __restrict__ Ea, const float* __restrict__ Eb,
    const float* __restrict__ W2, float* __restrict__ pbuf)
{
    __shared__ float eaj[32][68];   // stride 68 = 4 mod 32 banks: <=2-way, free
    __shared__ float eai[32][68];
    __shared__ float ebi[32][68];
    __shared__ float ebj[32][68];
    __shared__ float w0_s[128], w1_s[128];

    const int tid = threadIdx.x;
    const int tx  = tid & 15;
    const int ty  = tid >> 4;

    int tt = blockIdx.x, bi = 0, rem = NT;          // triangular decode
    while (tt >= rem) { tt -= rem; --rem; ++bi; }
    const int bj    = bi + tt;
    const int ibase = bi * 32;
    const int jbase = bj * 32;
    const int slice = HH / NZ;                      // 128
    const int k0    = blockIdx.y * slice;

    {   // stage W2 slice (32 float4 per channel)
        if (tid < 64) {
            const int c = tid >= 32, q = tid - c * 32;
            ((float4*)(c ? w1_s : w0_s))[q] = *(const float4*)&W2[c * HH + k0 + q * 4];
        }
    }

    float acc[2][2][2] = {};  // [ii][jj][c]

    for (int kb = 0; kb < slice; kb += 64) {
        __syncthreads();
        {   // stage 4 tiles x 32 rows x 64 floats = 2048 float4, 8/thread
            int p = tid;
#pragma unroll
            for (int it = 0; it < 8; ++it, p += 256) {
                const int tile = p >> 9;
                const int row  = (p >> 4) & 31;
                const int c4   = p & 15;
                float4 v;
                if      (tile == 0) v = *(const float4*)&Ea[(jbase + row) * HH + k0 + kb + c4 * 4];
                else if (tile == 1) v = *(const float4*)&Ea[(ibase + row) * HH + k0 + kb + c4 * 4];
                else if (tile == 2) v = *(const float4*)&Eb[(ibase + row) * HH + k0 + kb + c4 * 4];
                else                v = *(const float4*)&Eb[(jbase + row) * HH + k0 + kb + c4 * 4];
                if      (tile == 0) *(float4*)&eaj[row][c4 * 4] = v;
                else if (tile == 1) *(float4*)&eai[row][c4 * 4] = v;
                else if (tile == 2) *(float4*)&ebi[row][c4 * 4] = v;
                else                *(float4*)&ebj[row][c4 * 4] = v;
            }
        }
        __syncthreads();

#pragma unroll 4
        for (int h4 = 0; h4 < 16; ++h4) {
            const float4 Aj0 = *(const float4*)&eaj[tx][h4 * 4];
            const float4 Aj1 = *(const float4*)&eaj[tx + 16][h4 * 4];
            const float4 Bi0 = *(const float4*)&ebi[ty][h4 * 4];
            const float4 Bi1 = *(const float4*)&ebi[ty + 16][h4 * 4];
            const float4 Ai0 = *(const float4*)&eai[ty][h4 * 4];
            const float4 Ai1 = *(const float4*)&eai[ty + 16][h4 * 4];
            const float4 Bj0 = *(const float4*)&ebj[tx][h4 * 4];
            const float4 Bj1 = *(const float4*)&ebj[tx + 16][h4 * 4];
            const float4 w0  = *(const float4*)&w0_s[kb + h4 * 4];  // broadcast
            const float4 w1  = *(const float4*)&w1_s[kb + h4 * 4];

#define DO_H(AJ0, AJ1, BI0, BI1, AI0, AI1, BJ0, BJ1, W0V, W1V)        \
            {                                                          \
                const float d00 = __builtin_fmaf((BI0), (AJ0), 1.f);   \
                const float d01 = __builtin_fmaf((BI0), (AJ1), 1.f);   \
                const float d10 = __builtin_fmaf((BI1), (AJ0), 1.f);   \
                const float d11 = __builtin_fmaf((BI1), (AJ1), 1.f);   \
                const float e00 = __builtin_fmaf((AI0), (BJ0), 1.f);   \
                const float e01 = __builtin_fmaf((AI0), (BJ1), 1.f);   \
                const float e10 = __builtin_fmaf((AI1), (BJ0), 1.f);   \
                const float e11 = __builtin_fmaf((AI1), (BJ1), 1.f);   \
                const float dp0 = d00 * d01, dp1 = d10 * d11;          \
                const float DR  = __builtin_amdgcn_rcpf(dp0 * dp1);    \
                const float dq0 = DR * dp1, dq1 = DR * dp0;            \
                const float rd00 = dq0 * d01, rd01 = dq0 * d00;        \
                const float rd10 = dq1 * d11, rd11 = dq1 * d10;        \
                const float ep0 = e00 * e01, ep1 = e10 * e11;          \
                const float ER  = __builtin_amdgcn_rcpf(ep0 * ep1);    \
                const float eq0 = ER * ep1, eq1 = ER * ep0;            \
                const float re00 = eq0 * e01, re01 = eq0 * e00;        \
                const float re10 = eq1 * e11, re11 = eq1 * e10;        \
                const float u00 = rd00 + re00, u01 = rd01 + re01;      \
                const float u10 = rd10 + re10, u11 = rd11 + re11;      \
                acc[0][0][0] = __builtin_fmaf(u00, (W0V), acc[0][0][0]); \
                acc[0][0][1] = __builtin_fmaf(u00, (W1V), acc[0][0][1]); \
                acc[0][1][0] = __builtin_fmaf(u01, (W0V), acc[0][1][0]); \
                acc[0][1][1] = __builtin_fmaf(u01, (W1V), acc[0][1][1]); \
                acc[1][0][0] = __builtin_fmaf(u10, (W0V), acc[1][0][0]); \
                acc[1][0][1] = __builtin_fmaf(u10, (W1V), acc[1][0][1]); \
                acc[1][1][0] = __builtin_fmaf(u11, (W0V), acc[1][1][0]); \
                acc[1][1][1] = __builtin_fmaf(u11, (W1V), acc[1][1][1]); \
            }
            DO_H(Aj0.x, Aj1.x, Bi0.x, Bi1.x, Ai0.x, Ai1.x, Bj0.x, Bj1.x, w0.x, w1.x)
            DO_H(Aj0.y, Aj1.y, Bi0.y, Bi1.y, Ai0.y, Ai1.y, Bj0.y, Bj1.y, w0.y, w1.y)
            DO_H(Aj0.z, Aj1.z, Bi0.z, Bi1.z, Ai0.z, Ai1.z, Bj0.z, Bj1.z, w0.z, w1.z)
            DO_H(Aj0.w, Aj1.w, Bi0.w, Bi1.w, Ai0.w, Ai1.w, Bj0.w, Bj1.w, w0.w, w1.w)
#undef DO_H
        }
    }

    float* pb = pbuf + ((size_t)blockIdx.y * NTRI + blockIdx.x) * 2048;
#pragma unroll
    for (int ii = 0; ii < 2; ++ii)
#pragma unroll
        for (int jj = 0; jj < 2; ++jj) {
            const int li = ty + ii * 16, lj = tx + jj * 16;
            *(float2*)&pb[(li * 32 + lj) * 2] =
                make_float2(acc[ii][jj][0], acc[ii][jj][1]);
        }
}

// ---------------------------------------------------------------------------
// Kernel 3: combine (R6 structure: 1088 blocks, 1 thread/elem, unrolled NZ).
//   out = wsum[c] + b2[c] - sum_z pbuf; scatter to (i,j) and (j,i).
// ---------------------------------------------------------------------------
__global__ __launch_bounds__(256) void combine_kernel(
    const float* __restrict__ pbuf, const float* __restrict__ b2,
    const float* __restrict__ wsum, float* __restrict__ out)
{
    const int idx   = blockIdx.x * 256 + threadIdx.x;   // 0 .. 136*2048-1
    const int t     = idx >> 11;
    const int local = idx & 2047;
    int tt = t, bi = 0, rem = NT;
    while (tt >= rem) { tt -= rem; --rem; ++bi; }
    const int bj = bi + tt;

    float s = 0.f;
#pragma unroll
    for (int z = 0; z < NZ; ++z)
        s += pbuf[((size_t)z * NTRI + t) * 2048 + local];

    const int li = local >> 6;
    const int lj = (local >> 1) & 31;
    const int c  = local & 1;
    const float v = wsum[c] + b2[c] - s;

    const int i = bi * 32 + li;
    const int j = bj * 32 + lj;
    out[(i * LL + j) * 2 + c] = v;
    out[(j * LL + i) * 2 + c] = v;   // diagonal tiles: same-value rewrite, benign
}

extern "C" void kernel_launch(void* const* d_in, const int* in_sizes, int n_in,
                              void* d_out, int out_size, void* d_ws, size_t ws_size,
                              hipStream_t stream)
{
    const float* lm = (const float*)d_in[0];
    const float* W1 = (const float*)d_in[1];
    const float* b1 = (const float*)d_in[2];
    const float* W2 = (const float*)d_in[3];
    const float* b2 = (const float*)d_in[4];
    float* out = (float*)d_out;

    char* ws = (char*)d_ws;
    float*  Ea   = (float*)ws;                           // 2 MB
    float*  Eb   = (float*)(ws + (2u << 20));            // 2 MB
    ushort* lm16 = (ushort*)(ws + (4u << 20));           // 1 MB
    ushort* B16  = (ushort*)(ws + (5u << 20));           // 4 MB
    float*  wsum = (float*)(ws + (9u << 20));            // 256 B
    float*  pbuf = (float*)(ws + (9u << 20) + 256);      // 8 * 1.11 MB = 8.9 MB

    convert_kernel<<<1281, 256, 0, stream>>>(lm, W1, W2, lm16, B16, wsum);
    proj_mfma_kernel<<<256, 256, 0, stream>>>(lm16, B16, b1, Ea, Eb);
    pair_kernel<<<dim3(NTRI, NZ), 256, 0, stream>>>(Ea, Eb, W2, pbuf);
    combine_kernel<<<(NTRI * 2048) / 256, 256, 0, stream>>>(pbuf, b2, wsum, out);
}

// Round 10
// 129.505 us; speedup vs baseline: 1.4303x; 1.0472x over previous
//
#include <hip/hip_runtime.h>
#include <hip/hip_bf16.h>

#define HH 1024
#define LL 512
#define NT 16              // 512/32 row-tiles
#define NTRI 136           // NT*(NT+1)/2 triangular tiles

typedef __attribute__((ext_vector_type(8))) short bf16x8;
typedef __attribute__((ext_vector_type(4))) float f32x4;
typedef __attribute__((ext_vector_type(2))) float f32x2;

static constexpr float C_EXP = 2.8853900817779268f; // 2*log2(e)

// pack 8 fp32 -> 8 bf16 (RNE) as uint4
static __device__ __forceinline__ uint4 pack8(float4 a, float4 b) {
    union { uint4 u; __hip_bfloat162 h[4]; } r;
    r.h[0] = __float22bfloat162_rn(make_float2(a.x, a.y));
    r.h[1] = __float22bfloat162_rn(make_float2(a.z, a.w));
    r.h[2] = __float22bfloat162_rn(make_float2(b.x, b.y));
    r.h[3] = __float22bfloat162_rn(make_float2(b.z, b.w));
    return r.u;
}

// ---------------------------------------------------------------------------
// Kernel 0: fp32->bf16 convert (lm 1MB, W1 4MB) + wsum[c] = sum_h W2[c,h].
// ---------------------------------------------------------------------------
__global__ __launch_bounds__(256) void convert_kernel(
    const float* __restrict__ lm, const float* __restrict__ W1,
    const float* __restrict__ W2,
    ushort* __restrict__ lm16, ushort* __restrict__ B16, float* __restrict__ wsum)
{
    const int b = blockIdx.x;
    if (b == 1280) {
        const int tid = threadIdx.x;
        if (tid < 128) {
            const int c = tid >> 6, l = tid & 63;
            float s = 0.f;
            for (int q = l; q < 256; q += 64) {
                const float4 v = *(const float4*)&W2[c * HH + q * 4];
                s += v.x + v.y + v.z + v.w;
            }
#pragma unroll
            for (int off = 32; off; off >>= 1) s += __shfl_down(s, off, 64);
            if (l == 0) wsum[c] = s;
        }
        return;
    }
    const int q = b * 256 + threadIdx.x;            // 8-elem group
    if (q < 65536) {                                // lm: 512*1024/8
        const float4 a = *(const float4*)&lm[q * 8];
        const float4 c = *(const float4*)&lm[q * 8 + 4];
        ((uint4*)lm16)[q] = pack8(a, c);
    } else {
        const int p = q - 65536;                    // 0..262143
        const int n = p >> 7, k8 = (p & 127) * 8;
        const float* src = &W1[(n & 1023) * 2048 + (n >> 10) * 1024 + k8];
        ((uint4*)B16)[p] = pack8(*(const float4*)src, *(const float4*)(src + 4));
    }
}

// ---------------------------------------------------------------------------
// Kernel 1: bf16 MFMA projection. Tile 64m x 64n, BK=128 (8 barriered iters),
// grid 256 = 1/CU. XCD swizzle for L2 locality.
//   n < 1024:  Ea[m][n] = exp2(C*(acc+b1[n]));  else Eb[m][n-1024] = exp2(C*acc)
// ---------------------------------------------------------------------------
__global__ __launch_bounds__(256, 4) void proj_mfma_kernel(
    const ushort* __restrict__ lm16, const ushort* __restrict__ B16,
    const float* __restrict__ b1, float* __restrict__ Ea, float* __restrict__ Eb)
{
    __shared__ ushort As[64][136];  // 136 us = 68 dw = 4 mod 32 banks: <=2-way, free
    __shared__ ushort Bs[64][136];

    const int tid  = threadIdx.x;
    const int lane = tid & 63;
    const int w    = tid >> 6;
    const int b    = blockIdx.x;          // 0..255
    const int xcd  = b & 7;
    const int idx  = b >> 3;              // 0..31
    const int nbase = (xcd * 4 + (idx & 3)) * 64;   // 0..2047
    const int mbase = (idx >> 2) * 64;              // 0..448
    const int wm   = w * 16;

    const int frow = lane & 15;
    const int q8   = (lane >> 4) * 8;

    f32x4 acc[4] = {};

    for (int kb = 0; kb < HH; kb += 128) {
        __syncthreads();
        {   // As/Bs: 64 rows x 128 bf16 = 1024 uint4 slots each, 4/thread each
            int p = tid;
#pragma unroll
            for (int it = 0; it < 4; ++it, p += 256) {
                const int row = p >> 4, c8 = (p & 15) * 8;
                *(uint4*)&As[row][c8] = *(const uint4*)&lm16[(mbase + row) * HH + kb + c8];
                *(uint4*)&Bs[row][c8] = *(const uint4*)&B16[(nbase + row) * HH + kb + c8];
            }
        }
        __syncthreads();

#pragma unroll
        for (int s = 0; s < 4; ++s) {
            const bf16x8 a = *(const bf16x8*)&As[wm + frow][s * 32 + q8];
#pragma unroll
            for (int nf = 0; nf < 4; ++nf) {
                const bf16x8 bb = *(const bf16x8*)&Bs[nf * 16 + frow][s * 32 + q8];
                acc[nf] = __builtin_amdgcn_mfma_f32_16x16x32_bf16(a, bb, acc[nf], 0, 0, 0);
            }
        }
    }

    // D mapping: col=lane&15 (n), row=(lane>>4)*4+reg (m)
    const int col = lane & 15;
    const int rq  = (lane >> 4) * 4;
    const int m0  = mbase + wm + rq;
    const bool isA = nbase < HH;          // block-uniform
#pragma unroll
    for (int nf = 0; nf < 4; ++nf) {
        const int nn = (nbase + nf * 16 + col) & 1023;
        if (isA) {
            const float bb = b1[nn];
#pragma unroll
            for (int r = 0; r < 4; ++r)
                Ea[(m0 + r) * HH + nn] = __builtin_amdgcn_exp2f(C_EXP * (acc[nf][r] + bb));
        } else {
#pragma unroll
            for (int r = 0; r < 4; ++r)
                Eb[(m0 + r) * HH + nn] = __builtin_amdgcn_exp2f(C_EXP * acc[nf][r]);
        }
    }
}

// ---------------------------------------------------------------------------
// Kernel 2: triangular pairwise contraction, inner math on float2 ext-vectors
// to force v_pk_*_f32 (gfx950 packed fp32 = 2x scalar rate; the 157TF peak
// requires it). W2 staged interleaved {w0,w1} so c-channel acc-fma is one
// v_pk_fma. Batched rcp (1 per 4 denominators, per direction).
// Block = (bi<=bj) 32x32 tile pair x one h-slice (slice = HH/nz).
// ---------------------------------------------------------------------------
__global__ __launch_bounds__(256, 4) void pair_kernel(
    const float* __restrict__ Ea, const float* __restrict__ Eb,
    const float* __restrict__ W2, float* __restrict__ pbuf, int slice)
{
    __shared__ float eaj[32][68];   // stride 68 = 4 mod 32 banks: <=2-way, free
    __shared__ float eai[32][68];
    __shared__ float ebi[32][68];
    __shared__ float ebj[32][68];
    __shared__ f32x2 ws2[128];      // interleaved {w0[h], w1[h]}

    const int tid = threadIdx.x;
    const int tx  = tid & 15;
    const int ty  = tid >> 4;

    int tt = blockIdx.x, bi = 0, rem = NT;          // triangular decode
    while (tt >= rem) { tt -= rem; --rem; ++bi; }
    const int bj    = bi + tt;
    const int ibase = bi * 32;
    const int jbase = bj * 32;
    const int k0    = blockIdx.y * slice;

    if (tid < slice)   // stage W2 interleaved
        ws2[tid] = (f32x2){W2[k0 + tid], W2[HH + k0 + tid]};

    f32x2 acc2[2][2] = {};  // [ii][jj], lanes = c-channels
    const f32x2 one2 = {1.f, 1.f};

    for (int kb = 0; kb < slice; kb += 64) {
        __syncthreads();
        {   // stage 4 tiles x 32 rows x 64 floats = 2048 float4, 8/thread
            int p = tid;
#pragma unroll
            for (int it = 0; it < 8; ++it, p += 256) {
                const int tile = p >> 9;
                const int row  = (p >> 4) & 31;
                const int c4   = p & 15;
                float4 v;
                if      (tile == 0) v = *(const float4*)&Ea[(jbase + row) * HH + k0 + kb + c4 * 4];
                else if (tile == 1) v = *(const float4*)&Ea[(ibase + row) * HH + k0 + kb + c4 * 4];
                else if (tile == 2) v = *(const float4*)&Eb[(ibase + row) * HH + k0 + kb + c4 * 4];
                else                v = *(const float4*)&Eb[(jbase + row) * HH + k0 + kb + c4 * 4];
                if      (tile == 0) *(float4*)&eaj[row][c4 * 4] = v;
                else if (tile == 1) *(float4*)&eai[row][c4 * 4] = v;
                else if (tile == 2) *(float4*)&ebi[row][c4 * 4] = v;
                else                *(float4*)&ebj[row][c4 * 4] = v;
            }
        }
        __syncthreads();

#pragma unroll 4
        for (int h4 = 0; h4 < 16; ++h4) {
            const float4 Aj0 = *(const float4*)&eaj[tx][h4 * 4];
            const float4 Aj1 = *(const float4*)&eaj[tx + 16][h4 * 4];
            const float4 Bi0 = *(const float4*)&ebi[ty][h4 * 4];
            const float4 Bi1 = *(const float4*)&ebi[ty + 16][h4 * 4];
            const float4 Ai0 = *(const float4*)&eai[ty][h4 * 4];
            const float4 Ai1 = *(const float4*)&eai[ty + 16][h4 * 4];
            const float4 Bj0 = *(const float4*)&ebj[tx][h4 * 4];
            const float4 Bj1 = *(const float4*)&ebj[tx + 16][h4 * 4];
            const f32x4 wA = *(const f32x4*)&ws2[kb + h4 * 4];      // {w01[h0], w01[h1]}
            const f32x4 wB = *(const f32x4*)&ws2[kb + h4 * 4 + 2];  // {w01[h2], w01[h3]}

#define DO_H(AJ0v, AJ1v, BI0v, BI1v, AI0v, AI1v, BJ0v, BJ1v, W01)            \
            {                                                                 \
                const f32x2 Aj = {AJ0v, AJ1v};                                \
                const f32x2 Bj = {BJ0v, BJ1v};                                \
                const f32x2 d0 = __builtin_elementwise_fma((f32x2){BI0v, BI0v}, Aj, one2); \
                const f32x2 d1 = __builtin_elementwise_fma((f32x2){BI1v, BI1v}, Aj, one2); \
                const f32x2 e0 = __builtin_elementwise_fma((f32x2){AI0v, AI0v}, Bj, one2); \
                const f32x2 e1 = __builtin_elementwise_fma((f32x2){AI1v, AI1v}, Bj, one2); \
                const float dp0 = d0.x * d0.y, dp1 = d1.x * d1.y;             \
                const float ep0 = e0.x * e0.y, ep1 = e1.x * e1.y;             \
                const float DR = __builtin_amdgcn_rcpf(dp0 * dp1);            \
                const float ER = __builtin_amdgcn_rcpf(ep0 * ep1);            \
                const f32x2 dq = (f32x2){DR, DR} * (f32x2){dp1, dp0};         \
                const f32x2 eq = (f32x2){ER, ER} * (f32x2){ep1, ep0};         \
                const f32x2 u0 = (f32x2){dq.x, dq.x} * d0.yx + (f32x2){eq.x, eq.x} * e0.yx; \
                const f32x2 u1 = (f32x2){dq.y, dq.y} * d1.yx + (f32x2){eq.y, eq.y} * e1.yx; \
                acc2[0][0] = __builtin_elementwise_fma((f32x2){u0.x, u0.x}, (W01), acc2[0][0]); \
                acc2[0][1] = __builtin_elementwise_fma((f32x2){u0.y, u0.y}, (W01), acc2[0][1]); \
                acc2[1][0] = __builtin_elementwise_fma((f32x2){u1.x, u1.x}, (W01), acc2[1][0]); \
                acc2[1][1] = __builtin_elementwise_fma((f32x2){u1.y, u1.y}, (W01), acc2[1][1]); \
            }
            DO_H(Aj0.x, Aj1.x, Bi0.x, Bi1.x, Ai0.x, Ai1.x, Bj0.x, Bj1.x, wA.xy)
            DO_H(Aj0.y, Aj1.y, Bi0.y, Bi1.y, Ai0.y, Ai1.y, Bj0.y, Bj1.y, wA.zw)
            DO_H(Aj0.z, Aj1.z, Bi0.z, Bi1.z, Ai0.z, Ai1.z, Bj0.z, Bj1.z, wB.xy)
            DO_H(Aj0.w, Aj1.w, Bi0.w, Bi1.w, Ai0.w, Ai1.w, Bj0.w, Bj1.w, wB.zw)
#undef DO_H
        }
    }

    float* pb = pbuf + ((size_t)blockIdx.y * NTRI + blockIdx.x) * 2048;
#pragma unroll
    for (int ii = 0; ii < 2; ++ii)
#pragma unroll
        for (int jj = 0; jj < 2; ++jj) {
            const int li = ty + ii * 16, lj = tx + jj * 16;
            *(f32x2*)&pb[(li * 32 + lj) * 2] = acc2[ii][jj];
        }
}

// ---------------------------------------------------------------------------
// Kernel 3: combine: out = wsum[c] + b2[c] - sum_z pbuf; 1088 blocks,
// two-way ILP on the z-accumulation. Scatter to (i,j) and (j,i).
// ---------------------------------------------------------------------------
__global__ __launch_bounds__(256) void combine_kernel(
    const float* __restrict__ pbuf, const float* __restrict__ b2,
    const float* __restrict__ wsum, float* __restrict__ out, int nz)
{
    const int idx   = blockIdx.x * 256 + threadIdx.x;   // 0 .. 136*2048-1
    const int t     = idx >> 11;
    const int local = idx & 2047;
    int tt = t, bi = 0, rem = NT;
    while (tt >= rem) { tt -= rem; --rem; ++bi; }
    const int bj = bi + tt;

    float s0 = 0.f, s1 = 0.f;
    for (int z = 0; z < nz; z += 2) {   // nz is even
        s0 += pbuf[((size_t)z * NTRI + t) * 2048 + local];
        s1 += pbuf[((size_t)(z + 1) * NTRI + t) * 2048 + local];
    }
    const float s = s0 + s1;

    const int li = local >> 6;
    const int lj = (local >> 1) & 31;
    const int c  = local & 1;
    const float v = wsum[c] + b2[c] - s;

    const int i = bi * 32 + li;
    const int j = bj * 32 + lj;
    out[(i * LL + j) * 2 + c] = v;
    out[(j * LL + i) * 2 + c] = v;   // diagonal tiles: same-value rewrite, benign
}

extern "C" void kernel_launch(void* const* d_in, const int* in_sizes, int n_in,
                              void* d_out, int out_size, void* d_ws, size_t ws_size,
                              hipStream_t stream)
{
    const float* lm = (const float*)d_in[0];
    const float* W1 = (const float*)d_in[1];
    const float* b1 = (const float*)d_in[2];
    const float* W2 = (const float*)d_in[3];
    const float* b2 = (const float*)d_in[4];
    float* out = (float*)d_out;

    char* ws = (char*)d_ws;
    float*  Ea   = (float*)ws;                           // 2 MB
    float*  Eb   = (float*)(ws + (2u << 20));            // 2 MB
    float*  wsum = (float*)(ws + (4u << 20));            // 256 B
    // Union region at 4MB+256: {lm16 1MB, B16 4MB} live until proj finishes;
    // pbuf (written by pair, after proj) aliases over them.
    char*   ub   = ws + (4u << 20) + 256;
    ushort* lm16 = (ushort*)ub;
    ushort* B16  = (ushort*)(ub + (1u << 20));
    float*  pbuf = (float*)ub;

    const size_t ubase  = (4u << 20) + 256;
    const size_t pb16   = (size_t)16 * NTRI * 2048 * 4;  // 17.8 MB
    const int nz = (ws_size >= ubase + pb16) ? 16 : 8;   // ws_size const/session
    const int slice = HH / nz;

    convert_kernel<<<1281, 256, 0, stream>>>(lm, W1, W2, lm16, B16, wsum);
    proj_mfma_kernel<<<256, 256, 0, stream>>>(lm16, B16, b1, Ea, Eb);
    pair_kernel<<<dim3(NTRI, nz), 256, 0, stream>>>(Ea, Eb, W2, pbuf, slice);
    combine_kernel<<<(NTRI * 2048) / 256, 256, 0, stream>>>(pbuf, b2, wsum, out, nz);
}